// Round 8
// baseline (76.119 us; speedup 1.0000x reference)
//
#include <hip/hip_runtime.h>

// MesoLayer R7: back to global_load_lds staging (R5's proven path), but with
// 4 resident blocks/CU for demand smoothing / latency hiding.
// Block = 256 threads = 128 rows; 16 phases x 8-row chunks (780 float4).
// 2 stage buffers (1-deep prefetch) + 2 outbufs = 28864 B LDS -> 4 blocks/CU
// (16 waves/CU), independently barriered -> interleaved demand.
// Phase p: wait vmcnt(exact) -> lgkm0 -> barrier -> stage(p+1) -> flush(p-1)
//          -> compute(p).
// Steady-state wait = vmcnt(1) uniformly (only the flush(p-2) store is newer
// than chunk p's last load); p=0,1 use vmcnt(0) (nothing newer exists).

#define GLL16(gp, lp)                                                   \
  __builtin_amdgcn_global_load_lds(                                     \
      (const __attribute__((address_space(1))) void*)(gp),              \
      (__attribute__((address_space(3))) void*)(lp), 16, 0, 0)

static __device__ __forceinline__ float xsum(float a) {
  a += __shfl_xor(a, 1, 64);
  a += __shfl_xor(a, 2, 64);
  a += __shfl_xor(a, 4, 64);
  return a;
}
static __device__ __forceinline__ float xmax(float a) {
  a = fmaxf(a, __shfl_xor(a, 1, 64));
  a = fmaxf(a, __shfl_xor(a, 2, 64));
  a = fmaxf(a, __shfl_xor(a, 4, 64));
  return a;
}

// 64-lane segment (R6-proven): lane (q=ln&7, r=(ln>>3)&7) covers row r,
// j in {q, q+8, ...}; reduce over q via shfl_xor 1/2/4; true global max ->
// single-pass exp. Mt = upper-tri of M = W W^T.
template<int L, int SEGOFF, int OUTOFF>
__device__ __forceinline__ void seg64(const float* __restrict__ bp, int q,
                                      const float (&Mt)[15],
                                      float* __restrict__ ob) {
  constexpr int T[5][5] = {{0, 1, 2, 3, 4},  {1, 5, 6, 7, 8},
                           {2, 6, 9, 10, 11}, {3, 7, 10, 12, 13},
                           {4, 8, 11, 13, 14}};
  constexpr int NJ = (L + 7) / 8;
  const bool lastv = (q + 8 * (NJ - 1)) < L;

  float s[NJ][5];
#pragma unroll
  for (int k = 0; k < NJ; ++k) {
    int j = q + 8 * k;
    if (j > L - 1) j = L - 1;  // only last k can clamp
#pragma unroll
    for (int g = 0; g < 5; ++g) s[k][g] = bp[SEGOFF + j * 5 + g];
  }
#pragma unroll
  for (int g = 0; g < 5; ++g) s[NJ - 1][g] = lastv ? s[NJ - 1][g] : 0.f;

  float ssl[5];
#pragma unroll
  for (int g = 0; g < 5; ++g) {
    float a = s[0][g];
#pragma unroll
    for (int k = 1; k < NJ; ++k) a += s[k][g];
    ssl[g] = xsum(a);  // full subsum on all lanes
  }

  float v[5];
#pragma unroll
  for (int g = 0; g < 5; ++g) {
    float a = Mt[T[g][0]] * ssl[0];
#pragma unroll
    for (int h = 1; h < 5; ++h) a += Mt[T[g][h]] * ssl[h];
    v[g] = a;
  }

  float sc[NJ];
#pragma unroll
  for (int k = 0; k < NJ; ++k) {
    float a = s[k][0] * v[0];
#pragma unroll
    for (int g = 1; g < 5; ++g) a += s[k][g] * v[g];
    sc[k] = a;
  }
  sc[NJ - 1] = lastv ? sc[NJ - 1] : -3.0e38f;

  float ml = sc[0];
#pragma unroll
  for (int k = 1; k < NJ; ++k) ml = fmaxf(ml, sc[k]);
  float m = xmax(ml);

  float d = 0.f, pl[5] = {0.f, 0.f, 0.f, 0.f, 0.f};
#pragma unroll
  for (int k = 0; k < NJ; ++k) {
    float e = __expf(sc[k] - m);  // masked k: exp(-huge)=0
    d += e;
#pragma unroll
    for (int g = 0; g < 5; ++g) pl[g] += e * s[k][g];
  }
  d = xsum(d);
  float inv = 1.0f / d;
#pragma unroll
  for (int g = 0; g < 5; ++g) pl[g] = xsum(pl[g]);
  if (q == 0) {
#pragma unroll
    for (int g = 0; g < 5; ++g) ob[OUTOFF + g] = pl[g] * inv;
  }
}

// LDS floats: buf0 [0,3328) | buf1 [3328,6656)  (each: 780 fl4 data + 52 fl4
// pad for the wave-uniform tail) | out0 [6656,6936) | out1 [6936,7216).
// Total 28864 B -> 4+ blocks/CU.
__global__ __launch_bounds__(256, 4) void meso_kernel(
    const float* __restrict__ x, const float* __restrict__ w,
    float* __restrict__ out) {
  __shared__ __align__(16) float smf[7216];
  float4* sm4 = (float4*)smf;
  float2* sm2 = (float2*)smf;
  const int t = threadIdx.x;
  const int wv = t >> 6, ln = t & 63, q = ln & 7, r = (ln >> 3) & 7;
  const float4* xp4 = (const float4*)x + (size_t)blockIdx.x * 12480;  // 128*390/4
  float2* o2 = (float2*)out + (size_t)blockIdx.x * 2240;              // 128*35/2

  // Stage chunk c (780 fl4) into buf b. 3 full-wave gll (per-lane LDS ptr ->
  // readfirstlane base, HW adds lane*16B) + wave0-uniform tail: lanes 0..11
  // real, lanes 12..63 re-read one in-bounds fl4 into the buffer pad.
  auto stage = [&](int c, int b) {
    const float4* g = xp4 + c * 780;
    float4* l = sm4 + b * 832;
#pragma unroll
    for (int i = 0; i < 3; ++i) GLL16(g + i * 256 + t, l + i * 256 + t);
    if (wv == 0) {
      int gi = (ln < 12) ? 768 + ln : 779;  // dummies: 1 shared line
      GLL16(g + gi, l + 768 + ln);          // lands in pad [780,832)
    }
  };

  stage(0, 0);  // chunk 0 in flight...

  // ...while Mt = upper-tri(W W^T) resolves from uniform scalar loads.
  float Mt[15];
  {
    int i = 0;
#pragma unroll
    for (int g = 0; g < 5; ++g)
#pragma unroll
      for (int h = g; h < 5; ++h, ++i) {
        float a = 0.f;
#pragma unroll
        for (int k = 0; k < 10; ++k) a += w[g * 10 + k] * w[h * 10 + k];
        Mt[i] = a;
      }
  }

#pragma unroll 1
  for (int p = 0; p < 16; ++p) {
    // Counted wait for chunk p (audited): p=0 -> stage(0) is everything;
    // p=1 -> stage(1) is newest (phase0 has no flush); p>=2 -> only
    // flush(p-2)'s store was issued after stage(p)'s last load.
    if (p < 2) asm volatile("s_waitcnt vmcnt(0)" ::: "memory");
    else       asm volatile("s_waitcnt vmcnt(1)" ::: "memory");
    asm volatile("s_waitcnt lgkmcnt(0)" ::: "memory");
    __builtin_amdgcn_s_barrier();
    // Invariants: chunk p in buf[p&1]; compute(p-1) LDS reads drained (so
    // stage(p+1) may overwrite buf[(p+1)&1]); outbuf[(p-1)&1] complete.

    if (p < 15) stage(p + 1, (p + 1) & 1);
    if (p > 0 && ln < 35) {
      // flush(p-1): 140 float2, wave w stores its own 35 -> exactly 1 store
      // per wave per phase (uniform vmcnt accounting).
      o2[(p - 1) * 140 + wv * 35 + ln] =
          sm2[3328 + ((p - 1) & 1) * 140 + wv * 35 + ln];
    }

    {
      const float* bp = smf + (p & 1) * 3328 + r * 390;
      float* ob = smf + 6656 + (p & 1) * 280 + r * 35;
      if (wv == 0) {
        seg64<25, 115, 15>(bp, q, Mt, ob);
      } else if (wv == 1) {
        seg64<12, 330, 30>(bp, q, Mt, ob);
        seg64<5,  0,   0 >(bp, q, Mt, ob);
      } else if (wv == 2) {
        seg64<9,  25,  5 >(bp, q, Mt, ob);
        seg64<9,  70,  10>(bp, q, Mt, ob);
      } else {
        seg64<9,  240, 20>(bp, q, Mt, ob);
        seg64<9,  285, 25>(bp, q, Mt, ob);
      }
    }
  }

  asm volatile("s_waitcnt lgkmcnt(0)" ::: "memory");
  __builtin_amdgcn_s_barrier();
  if (ln < 35)
    o2[15 * 140 + wv * 35 + ln] = sm2[3328 + 140 + wv * 35 + ln];
}

extern "C" void kernel_launch(void* const* d_in, const int* in_sizes, int n_in,
                              void* d_out, int out_size, void* d_ws, size_t ws_size,
                              hipStream_t stream) {
  const float* x = (const float*)d_in[0];
  const float* w = (const float*)d_in[1];
  float* out = (float*)d_out;
  int B = in_sizes[0] / 390;  // 131072
  int grid = B / 128;         // 1024 blocks = 4/CU resident
  meso_kernel<<<grid, 256, 0, stream>>>(x, w, out);
}